// Round 1
// 305.601 us; speedup vs baseline: 1.0356x; 1.0356x over previous
//
#include <hip/hip_runtime.h>
#include <hip/hip_bf16.h>

#define NLAT_IN  480
#define NLON_IN  960
#define NLAT_OUT 721
#define NLON_OUT 1440
#define KSIZE    9
#define NNZ      20
#define CH       32   // C_IN == C_OUT == 32

typedef __bf16 bf16x8 __attribute__((ext_vector_type(8)));
typedef float  f32x4  __attribute__((ext_vector_type(4)));
typedef unsigned u32x4 __attribute__((ext_vector_type(4)));

__device__ __forceinline__ unsigned short f2bf(float f) {
    unsigned u = __float_as_uint(f);
    u += 0x7fffu + ((u >> 16) & 1u);   // round-to-nearest-even
    return (unsigned short)(u >> 16);
}

// ---------------------------------------------------------------------------
// Kernel 1: bilinear resample (480,960) -> (721,1440), channel-last bf16 out.
// Compute phase regrouped: each item = (w, 8-channel group) -> one 16B store.
// ---------------------------------------------------------------------------
#define W_TILE   180
#define IN_LD4   31            // 31 float4 = 124 input cols staged
#define LDS_PITCH 129

__global__ __launch_bounds__(256) void resample_kernel(
        const float* __restrict__ x,
        unsigned short* __restrict__ xr) {
    __shared__ float ld[2 * CH * LDS_PITCH];

    int h  = blockIdx.y;
    int bx = blockIdx.x;
    int wb = bx * W_TILE;
    int base_in = bx * (W_TILE * 2 / 3);   // = bx*120

    float pos_h = (float)h * (479.0f / 720.0f);
    int h0 = (int)floorf(pos_h);
    if (h0 < 0) h0 = 0;
    if (h0 > NLAT_IN - 2) h0 = NLAT_IN - 2;
    float fh = pos_h - (float)h0;

    const int t = threadIdx.x;
    for (int i = 0; i < 8; ++i) {
        int lin = i * 256 + t;             // [0, 1984)
        if (lin < 2 * CH * IN_LD4) {
            int r   = lin / (CH * IN_LD4);
            int rem = lin - r * (CH * IN_LD4);
            int c   = rem / IN_LD4;
            int j   = rem - c * IN_LD4;
            int src = base_in + 4 * j;
            if (src >= NLON_IN) src -= NLON_IN;      // only last block
            f32x4 v = *(const f32x4*)(x + ((size_t)c * NLAT_IN + h0 + r) * NLON_IN + src);
            float* dst = ld + (r * CH + c) * LDS_PITCH + 4 * j;
            dst[0] = v.x; dst[1] = v.y; dst[2] = v.z; dst[3] = v.w;
        }
    }
    __syncthreads();

    float ifh = 1.0f - fh;
    for (int i = 0; i < 3; ++i) {
        int d = i * 256 + t;               // [0, 768)
        if (d >= W_TILE * (CH / 8)) break; // 720 items
        int w_l = d >> 2;
        int cg  = d & 3;                   // channel group of 8
        int w = wb + w_l;
        float pos_w = (float)w * ((float)NLON_IN / (float)NLON_OUT);
        int w0 = (int)floorf(pos_w);
        float fw = pos_w - (float)w0;
        int wl0 = w0 - base_in;            // [0, 120]
        float ifw = 1.0f - fw;

        unsigned rr[4];
#pragma unroll
        for (int j = 0; j < 4; ++j) {
            int c = cg * 8 + j * 2;
            const float* r0 = ld + c * LDS_PITCH + wl0;
            const float* r1 = r0 + CH * LDS_PITCH;
            float v0 = ifh * (ifw * r0[0] + fw * r0[1]) + fh * (ifw * r1[0] + fw * r1[1]);
            const float* q0 = r0 + LDS_PITCH;
            const float* q1 = r1 + LDS_PITCH;
            float v1 = ifh * (ifw * q0[0] + fw * q0[1]) + fh * (ifw * q1[0] + fw * q1[1]);
            rr[j] = (unsigned)f2bf(v0) | ((unsigned)f2bf(v1) << 16);
        }
        u32x4 uv; uv[0] = rr[0]; uv[1] = rr[1]; uv[2] = rr[2]; uv[3] = rr[3];
        *(u32x4*)((unsigned*)xr + ((size_t)h * NLON_OUT + w) * (CH / 2) + cg * 4) = uv;
    }
}

// ---------------------------------------------------------------------------
// Kernel 2: weff[h][nz][oc][c] = sum_k weight[oc][c][k] * psi_vals[k][h][nz]
// Weight staged in LDS transposed to [k][oc][c]; block = 16 hnz.
// ---------------------------------------------------------------------------
__global__ __launch_bounds__(256) void weff_kernel(
        const float* __restrict__ weight,
        const float* __restrict__ psi_vals,
        unsigned short* __restrict__ weff) {
    __shared__ float wl[KSIZE * CH * CH];   // [k][oc][c]

    const int t = threadIdx.x;
    for (int i = 0; i < 9; ++i) {
        int lin = i * 256 + t;              // [0, 2304)
        if (lin < KSIZE * CH * CH / 4) {
            f32x4 v = *(const f32x4*)(weight + lin * 4);
            float vv[4] = {v.x, v.y, v.z, v.w};
#pragma unroll
            for (int q = 0; q < 4; ++q) {
                int l4 = lin * 4 + q;       // = (oc*CH + c)*KSIZE + k
                int k  = l4 % KSIZE;
                int occ = l4 / KSIZE;       // oc*CH + c
                wl[k * (CH * CH) + occ] = vv[q];
            }
        }
    }
    __syncthreads();

    int hnz = blockIdx.x * 16 + (t >> 4);
    int cp  = t & 15;
    if (hnz >= NLAT_OUT * NNZ) return;

    float p[KSIZE];
#pragma unroll
    for (int k = 0; k < KSIZE; ++k)
        p[k] = psi_vals[(size_t)k * (NLAT_OUT * NNZ) + hnz];

    unsigned* outp = (unsigned*)weff + (size_t)hnz * (CH * CH / 2) + cp;
#pragma unroll 4
    for (int oc = 0; oc < CH; ++oc) {
        float a0 = 0.f, a1 = 0.f;
        const float* wb = wl + oc * CH + cp * 2;
#pragma unroll
        for (int k = 0; k < KSIZE; ++k) {
            a0 += wb[k * (CH * CH)]     * p[k];
            a1 += wb[k * (CH * CH) + 1] * p[k];
        }
        outp[oc * 16] = (unsigned)f2bf(a0) | ((unsigned)f2bf(a1) << 16);
    }
}

// ---------------------------------------------------------------------------
// Kernel 3: disco conv via MFMA.
// Block = 512 thr (8 waves) owns 4 h-rows x 96 w-cols.
//   wave = (jh<<1)|wq : jh = h-row within block (0..3), wq = 48-col half.
// Staged tile: rows [h0-2, h0+5] x cols [wbase-16, wbase+112) x 32ch bf16
//   = 8*128*64 B = 64 KiB -> 2 blocks/CU = 16 waves/CU (vs 12 before).
// LDS XOR-swizzle (T2, both-sides form per rule #21): global_load_lds writes
//   linearly, so the 16B sub-block index q of each staged (col,q) is
//   pre-swizzled on the GLOBAL source address (q ^= (col>>1)&3), and the same
//   XOR is applied on the B-fragment read. Within a 16-lane phase the reads
//   now start at 8 distinct bank offsets x 2 lanes = conflict-free minimum
//   (was: col-stride 64 B -> 2 bank-groups -> 8-way conflict, 5.19M cycles).
// A-fragments (weff) software-pipelined depth-2 (2-slot rotation, full
//   unroll so all indices are static); nz=0,1 prologue issued BEFORE the
//   staging barrier so its latency hides under the vmcnt(0) drain.
// Fragment maps (HW-verified): A[m=lane&15][k=quad*8+j],
// B[k=quad*8+j][n=lane&15], D[row=quad*4+r][col=lane&15].
// ---------------------------------------------------------------------------
#define ST_ROWS 8
#define ST_COLS 128
#define HBLK4   181                  // ceil(721/4)
#define NPAIRD  (HBLK4 * 15)         // 2715
#define PER_XCD ((NPAIRD + 7) / 8)   // 340

__global__ __launch_bounds__(512, 4) void disco_kernel(
        const unsigned short* __restrict__ xr,     // [721][1440][32] bf16
        const unsigned short* __restrict__ weff,   // [721][20][32][32] bf16
        const int* __restrict__ psi_hi,            // [721][20]
        const int* __restrict__ psi_dw,            // [721][20]
        float* __restrict__ out) {                 // [32][721][1440]
    __shared__ unsigned short st[ST_ROWS * ST_COLS * CH];   // 64 KiB

    int bid = blockIdx.x;
    int xcd = bid & 7;
    int p   = xcd * PER_XCD + (bid >> 3);
    if (p >= NPAIRD) return;
    int hblk = p / 15;
    int wblk = p - hblk * 15;
    int h0        = hblk * 4;
    int wbase_blk = wblk * 96;

    int wave = threadIdx.x >> 6;
    int lane = threadIdx.x & 63;
    int l15  = lane & 15;
    int quad = lane >> 4;
    int c0   = quad * 8;
    int jh   = wave >> 1;          // h-row within block (0..3)
    int wq   = wave & 1;           // 48-col half

    int  h  = h0 + jh;
    bool hv = (h < NLAT_OUT);

    // Per-lane swizzled source offset within a 16-col (1024 B) chunk:
    // lane covers col = lane>>2, sub-block q = lane&3; fetch logical
    // (col, q ^ ((col>>1)&3)) so the linear LDS write lands it swizzled.
    int swz = ((lane >> 2) << 5) + (((lane & 3) ^ ((lane >> 3) & 3)) << 3);

    // ---- A prologue: prefetch nz=0,1 weff fragments + psi entries ----
    const unsigned short* weff_h = weff + (size_t)h * (NNZ * CH * CH);
    const int* hip_ = psi_hi + h * NNZ;
    const int* dwp  = psi_dw + h * NNZ;

    bf16x8 pa0[2], pa1[2];
    int phi[2], pdw[2];
    if (hv) {
#pragma unroll
        for (int q = 0; q < 2; ++q) {
            const unsigned short* wp = weff_h + q * (CH * CH);
            pa0[q] = *(const bf16x8*)(wp + l15 * CH + c0);
            pa1[q] = *(const bf16x8*)(wp + (16 + l15) * CH + c0);
            phi[q] = hip_[q];
            pdw[q] = dwp[q];
        }
    }

    // ---- stage 8 rows x 128 cols: 64 chunks of 16 cols (1 KiB each) ----
    int cstart = wbase_blk - 16;
    if (cstart < 0) cstart += NLON_OUT;     // multiple of 16
    for (int i = wave; i < ST_ROWS * (ST_COLS / 16); i += 8) {
        int r  = i >> 3;
        int ck = i & 7;
        int gh = h0 - 2 + r;
        gh = gh < 0 ? 0 : (gh > NLAT_OUT - 1 ? NLAT_OUT - 1 : gh);
        int gc = cstart + ck * 16;
        if (gc >= NLON_OUT) gc -= NLON_OUT;  // chunk never crosses the wrap
        const unsigned short* gp = xr + ((size_t)gh * NLON_OUT + gc) * CH + swz;
        unsigned short* lp = st + (r * ST_COLS + ck * 16) * CH;
        __builtin_amdgcn_global_load_lds(
            (const __attribute__((address_space(1))) void*)gp,
            (__attribute__((address_space(3))) void*)lp, 16, 0, 0);
    }
    __syncthreads();

    // ---- compute: this wave's single h-row, B-fragments from LDS ----
    if (hv) {
        f32x4 acc[2][3] = {};
        int wcol0 = 16 + wq * 48 + l15;      // LDS col of this lane, s=0

#pragma unroll
        for (int nz = 0; nz < NNZ; ++nz) {
            const int sl = nz & 1;           // static after full unroll
            bf16x8 a0 = pa0[sl];
            bf16x8 a1 = pa1[sl];
            int hi = phi[sl];
            int dw = pdw[sl];
            if (nz + 2 < NNZ) {              // refill slot 2 nz ahead
                const unsigned short* wp = weff_h + (nz + 2) * (CH * CH);
                pa0[sl] = *(const bf16x8*)(wp + l15 * CH + c0);
                pa1[sl] = *(const bf16x8*)(wp + (16 + l15) * CH + c0);
                phi[sl] = hip_[nz + 2];
                pdw[sl] = dwp[nz + 2];
            }
            int shift = dw > 720 ? dw - NLON_OUT : dw;   // data range: [-10,10]
            int rloc  = hi - h0 + 2;                     // [0, 7]
            int cbase = wcol0 + shift;                   // [6, 89]
            // read-side XOR select: ((col>>1)&3) is invariant under +s*16
            int sel   = ((((cbase >> 1) & 3) ^ quad) << 3);
            const unsigned short* bp =
                st + (size_t)rloc * (ST_COLS * CH) + cbase * CH + sel;
#pragma unroll
            for (int s = 0; s < 3; ++s) {
                bf16x8 b = *(const bf16x8*)(bp + s * 16 * CH);
                acc[0][s] = __builtin_amdgcn_mfma_f32_16x16x32_bf16(a0, b, acc[0][s], 0, 0, 0);
                acc[1][s] = __builtin_amdgcn_mfma_f32_16x16x32_bf16(a1, b, acc[1][s], 0, 0, 0);
            }
        }

#pragma unroll
        for (int hh = 0; hh < 2; ++hh)
#pragma unroll
            for (int s = 0; s < 3; ++s)
#pragma unroll
                for (int r = 0; r < 4; ++r) {
                    int oc = hh * 16 + quad * 4 + r;
                    int w  = wbase_blk + wq * 48 + s * 16 + l15;
                    out[((size_t)oc * NLAT_OUT + h) * NLON_OUT + w] = acc[hh][s][r];
                }
    }
}

// ---------------------------------------------------------------------------
extern "C" void kernel_launch(void* const* d_in, const int* in_sizes, int n_in,
                              void* d_out, int out_size, void* d_ws, size_t ws_size,
                              hipStream_t stream) {
    const float* x        = (const float*)d_in[0];
    const float* weight   = (const float*)d_in[1];
    const float* psi_vals = (const float*)d_in[2];
    const int*   psi_hi   = (const int*)d_in[3];
    const int*   psi_dw   = (const int*)d_in[4];
    float* out = (float*)d_out;

    // workspace: xr bf16 [721][1440][32] = 66,447,360 B, then
    // weff bf16 [721][20][32][32] = 29,532,160 B
    unsigned short* xr = (unsigned short*)d_ws;
    unsigned short* wf = (unsigned short*)((char*)d_ws + (size_t)NLAT_OUT * NLON_OUT * CH * 2);

    {
        dim3 grid(NLON_OUT / W_TILE, NLAT_OUT);   // 8 x 721
        resample_kernel<<<grid, 256, 0, stream>>>(x, xr);
    }
    {
        int nblk = (NLAT_OUT * NNZ + 15) / 16;    // 902
        weff_kernel<<<nblk, 256, 0, stream>>>(weight, psi_vals, wf);
    }
    {
        disco_kernel<<<8 * PER_XCD, 512, 0, stream>>>(xr, wf, psi_hi, psi_dw, out);
    }
}

// Round 2
// 304.291 us; speedup vs baseline: 1.0401x; 1.0043x over previous
//
#include <hip/hip_runtime.h>
#include <hip/hip_bf16.h>

#define NLAT_IN  480
#define NLON_IN  960
#define NLAT_OUT 721
#define NLON_OUT 1440
#define KSIZE    9
#define NNZ      20
#define CH       32   // C_IN == C_OUT == 32

typedef __bf16 bf16x8 __attribute__((ext_vector_type(8)));
typedef float  f32x4  __attribute__((ext_vector_type(4)));
typedef unsigned u32x4 __attribute__((ext_vector_type(4)));

__device__ __forceinline__ unsigned short f2bf(float f) {
    unsigned u = __float_as_uint(f);
    u += 0x7fffu + ((u >> 16) & 1u);   // round-to-nearest-even
    return (unsigned short)(u >> 16);
}

// ---------------------------------------------------------------------------
// Kernel 1 (fused): blocks [0, NBLK_WEFF) compute weff, blocks
// [NBLK_WEFF, NBLK_WEFF+5768) do the bilinear resample. The two passes are
// independent (weff: weight/psi -> wf; resample: x -> xr); fusing saves a
// launch and overlaps them on the device.
// ---------------------------------------------------------------------------
#define W_TILE   180
#define IN_LD4   31            // 31 float4 = 124 input cols staged
#define LDS_PITCH 129
#define NBLK_WEFF 902          // ceil(721*20 / 16)
#define NBLK_RES  (8 * NLAT_OUT)

__global__ __launch_bounds__(256) void pre_kernel(
        const float* __restrict__ x,
        const float* __restrict__ weight,
        const float* __restrict__ psi_vals,
        unsigned short* __restrict__ xr,
        unsigned short* __restrict__ weff) {
    __shared__ float smem[KSIZE * CH * CH];   // 9216 floats = 36,864 B (union)

    const int bid = blockIdx.x;
    const int t   = threadIdx.x;

    if (bid < NBLK_WEFF) {
        // ---- weff[h][nz][oc][c] = sum_k weight[oc][c][k] * psi_vals[k][h][nz]
        float* wl = smem;                    // [k][oc][c]
        for (int i = 0; i < 9; ++i) {
            int lin = i * 256 + t;           // [0, 2304)
            if (lin < KSIZE * CH * CH / 4) {
                f32x4 v = *(const f32x4*)(weight + lin * 4);
                float vv[4] = {v.x, v.y, v.z, v.w};
#pragma unroll
                for (int q = 0; q < 4; ++q) {
                    int l4 = lin * 4 + q;    // = (oc*CH + c)*KSIZE + k
                    int k  = l4 % KSIZE;
                    int occ = l4 / KSIZE;    // oc*CH + c
                    wl[k * (CH * CH) + occ] = vv[q];
                }
            }
        }
        __syncthreads();

        int hnz = bid * 16 + (t >> 4);
        int cp  = t & 15;
        if (hnz >= NLAT_OUT * NNZ) return;

        float p[KSIZE];
#pragma unroll
        for (int k = 0; k < KSIZE; ++k)
            p[k] = psi_vals[(size_t)k * (NLAT_OUT * NNZ) + hnz];

        unsigned* outp = (unsigned*)weff + (size_t)hnz * (CH * CH / 2) + cp;
#pragma unroll 4
        for (int oc = 0; oc < CH; ++oc) {
            float a0 = 0.f, a1 = 0.f;
            const float* wb = wl + oc * CH + cp * 2;
#pragma unroll
            for (int k = 0; k < KSIZE; ++k) {
                a0 += wb[k * (CH * CH)]     * p[k];
                a1 += wb[k * (CH * CH) + 1] * p[k];
            }
            outp[oc * 16] = (unsigned)f2bf(a0) | ((unsigned)f2bf(a1) << 16);
        }
        return;
    }

    // ---- resample: (480,960) -> (721,1440), channel-last bf16 out ----
    float* ld = smem;                        // uses 2*CH*LDS_PITCH = 8256 floats
    int bid2 = bid - NBLK_WEFF;
    int bx = bid2 & 7;
    int h  = bid2 >> 3;
    int wb = bx * W_TILE;
    int base_in = bx * (W_TILE * 2 / 3);     // = bx*120

    float pos_h = (float)h * (479.0f / 720.0f);
    int h0 = (int)floorf(pos_h);
    if (h0 < 0) h0 = 0;
    if (h0 > NLAT_IN - 2) h0 = NLAT_IN - 2;
    float fh = pos_h - (float)h0;

    for (int i = 0; i < 8; ++i) {
        int lin = i * 256 + t;               // [0, 1984)
        if (lin < 2 * CH * IN_LD4) {
            int r   = lin / (CH * IN_LD4);
            int rem = lin - r * (CH * IN_LD4);
            int c   = rem / IN_LD4;
            int j   = rem - c * IN_LD4;
            int src = base_in + 4 * j;
            if (src >= NLON_IN) src -= NLON_IN;      // only last block
            f32x4 v = *(const f32x4*)(x + ((size_t)c * NLAT_IN + h0 + r) * NLON_IN + src);
            float* dst = ld + (r * CH + c) * LDS_PITCH + 4 * j;
            dst[0] = v.x; dst[1] = v.y; dst[2] = v.z; dst[3] = v.w;
        }
    }
    __syncthreads();

    float ifh = 1.0f - fh;
    for (int i = 0; i < 3; ++i) {
        int d = i * 256 + t;                 // [0, 768)
        if (d >= W_TILE * (CH / 8)) break;   // 720 items
        int w_l = d >> 2;
        int cg  = d & 3;                     // channel group of 8
        int w = wb + w_l;
        float pos_w = (float)w * ((float)NLON_IN / (float)NLON_OUT);
        int w0 = (int)floorf(pos_w);
        float fw = pos_w - (float)w0;
        int wl0 = w0 - base_in;              // [0, 120]
        float ifw = 1.0f - fw;

        unsigned rr[4];
#pragma unroll
        for (int j = 0; j < 4; ++j) {
            int c = cg * 8 + j * 2;
            const float* r0 = ld + c * LDS_PITCH + wl0;
            const float* r1 = r0 + CH * LDS_PITCH;
            float v0 = ifh * (ifw * r0[0] + fw * r0[1]) + fh * (ifw * r1[0] + fw * r1[1]);
            const float* q0 = r0 + LDS_PITCH;
            const float* q1 = r1 + LDS_PITCH;
            float v1 = ifh * (ifw * q0[0] + fw * q0[1]) + fh * (ifw * q1[0] + fw * q1[1]);
            rr[j] = (unsigned)f2bf(v0) | ((unsigned)f2bf(v1) << 16);
        }
        u32x4 uv; uv[0] = rr[0]; uv[1] = rr[1]; uv[2] = rr[2]; uv[3] = rr[3];
        *(u32x4*)((unsigned*)xr + ((size_t)h * NLON_OUT + w) * (CH / 2) + cg * 4) = uv;
    }
}

// ---------------------------------------------------------------------------
// Kernel 2: disco conv via MFMA.
// Block = 256 thr (4 waves) owns 4 h-rows x 48 w-cols; each wave = one full
// h-row (s = 0..2 gives 48 cols, both MFMA M-halves -> all 32 oc).
// Staged tile: rows [h0-2, h0+5] x cols [wbase-16, wbase+64) x 32ch bf16
//   = 8*80*64 B = 40 KiB -> 4 blocks/CU = 16 waves/CU with FOUR independent
//   staging barriers per CU (vs 2 correlated ones before): one block's
//   vmcnt(0) drain hides under three others' compute.
// LDS XOR-swizzle (T2, both-sides, chunk-local so ST_COLS=80 is fine):
//   global source pre-swizzled (q ^= (col>>1)&3 within each 16-col chunk),
//   same XOR applied on the B-fragment read -> conflict-free minimum.
// A-fragments (weff) software-pipelined depth-4 (slots fully unrolled,
//   static indices): refill slack ~3 nz-bodies >= L2 latency.
// Fragment maps (HW-verified): A[m=lane&15][k=quad*8+j],
// B[k=quad*8+j][n=lane&15], D[row=quad*4+r][col=lane&15].
// ---------------------------------------------------------------------------
#define ST_ROWS 8
#define ST_COLS 80
#define WC      48
#define HBLK4   181                  // ceil(721/4)
#define NWBLK   (NLON_OUT / WC)      // 30
#define NPAIRD  (HBLK4 * NWBLK)      // 5430
#define PER_XCD ((NPAIRD + 7) / 8)   // 679

__global__ __launch_bounds__(256, 4) void disco_kernel(
        const unsigned short* __restrict__ xr,     // [721][1440][32] bf16
        const unsigned short* __restrict__ weff,   // [721][20][32][32] bf16
        const int* __restrict__ psi_hi,            // [721][20]
        const int* __restrict__ psi_dw,            // [721][20]
        float* __restrict__ out) {                 // [32][721][1440]
    __shared__ unsigned short st[ST_ROWS * ST_COLS * CH];   // 40 KiB

    int bid = blockIdx.x;
    int xcd = bid & 7;
    int p   = xcd * PER_XCD + (bid >> 3);
    if (p >= NPAIRD) return;
    int hblk = p / NWBLK;
    int wblk = p - hblk * NWBLK;
    int h0        = hblk * 4;
    int wbase_blk = wblk * WC;

    int wave = threadIdx.x >> 6;   // = jh, h-row within block (0..3)
    int lane = threadIdx.x & 63;
    int l15  = lane & 15;
    int quad = lane >> 4;
    int c0   = quad * 8;

    int  h  = h0 + wave;
    bool hv = (h < NLAT_OUT);

    // Per-lane swizzled source offset within a 16-col (1024 B) chunk:
    // lane covers col = lane>>2, sub-block q = lane&3; fetch logical
    // (col, q ^ ((col>>1)&3)) so the linear LDS write lands it swizzled.
    int swz = ((lane >> 2) << 5) + (((lane & 3) ^ ((lane >> 3) & 3)) << 3);

    // ---- stage 8 rows x 80 cols: 40 chunks of 16 cols (1 KiB each) ----
    int cstart = wbase_blk - 16;
    if (cstart < 0) cstart += NLON_OUT;     // multiple of 16
    for (int i = wave; i < ST_ROWS * (ST_COLS / 16); i += 4) {
        int r  = i / 5;
        int ck = i - r * 5;
        int gh = h0 - 2 + r;
        gh = gh < 0 ? 0 : (gh > NLAT_OUT - 1 ? NLAT_OUT - 1 : gh);
        int gc = cstart + ck * 16;
        if (gc >= NLON_OUT) gc -= NLON_OUT;  // chunk never crosses the wrap
        const unsigned short* gp = xr + ((size_t)gh * NLON_OUT + gc) * CH + swz;
        unsigned short* lp = st + (r * ST_COLS + ck * 16) * CH;
        __builtin_amdgcn_global_load_lds(
            (const __attribute__((address_space(1))) void*)gp,
            (__attribute__((address_space(3))) void*)lp, 16, 0, 0);
    }

    // ---- A prologue: prefetch nz=0..3 weff fragments + psi entries ----
    const unsigned short* weff_h = weff + (size_t)h * (NNZ * CH * CH);
    const int* hip_ = psi_hi + h * NNZ;
    const int* dwp  = psi_dw + h * NNZ;

    bf16x8 pa0[4], pa1[4];
    int phi[4], pdw[4];
    if (hv) {
#pragma unroll
        for (int q = 0; q < 4; ++q) {
            const unsigned short* wp = weff_h + q * (CH * CH);
            pa0[q] = *(const bf16x8*)(wp + l15 * CH + c0);
            pa1[q] = *(const bf16x8*)(wp + (16 + l15) * CH + c0);
            phi[q] = hip_[q];
            pdw[q] = dwp[q];
        }
    }
    __syncthreads();

    // ---- compute: this wave's single h-row, B-fragments from LDS ----
    if (hv) {
        f32x4 acc[2][3] = {};
        int wcol0 = 16 + l15;                // LDS col of this lane, s=0

#pragma unroll
        for (int nz = 0; nz < NNZ; ++nz) {
            const int sl = nz & 3;           // static after full unroll
            bf16x8 a0 = pa0[sl];
            bf16x8 a1 = pa1[sl];
            int hi = phi[sl];
            int dw = pdw[sl];
            if (nz + 4 < NNZ) {              // refill slot 4 nz ahead
                const unsigned short* wp = weff_h + (nz + 4) * (CH * CH);
                pa0[sl] = *(const bf16x8*)(wp + l15 * CH + c0);
                pa1[sl] = *(const bf16x8*)(wp + (16 + l15) * CH + c0);
                phi[sl] = hip_[nz + 4];
                pdw[sl] = dwp[nz + 4];
            }
            int shift = dw > 720 ? dw - NLON_OUT : dw;   // data range: [-10,10]
            int rloc  = hi - h0 + 2;                     // [0, 7]
            int cbase = wcol0 + shift;                   // [6, 41]
            // read-side XOR select: ((col>>1)&3) is invariant under +s*16
            int sel   = ((((cbase >> 1) & 3) ^ quad) << 3);
            const unsigned short* bp =
                st + (size_t)rloc * (ST_COLS * CH) + cbase * CH + sel;
#pragma unroll
            for (int s = 0; s < 3; ++s) {
                bf16x8 b = *(const bf16x8*)(bp + s * 16 * CH);
                acc[0][s] = __builtin_amdgcn_mfma_f32_16x16x32_bf16(a0, b, acc[0][s], 0, 0, 0);
                acc[1][s] = __builtin_amdgcn_mfma_f32_16x16x32_bf16(a1, b, acc[1][s], 0, 0, 0);
            }
        }

#pragma unroll
        for (int hh = 0; hh < 2; ++hh)
#pragma unroll
            for (int s = 0; s < 3; ++s)
#pragma unroll
                for (int r = 0; r < 4; ++r) {
                    int oc = hh * 16 + quad * 4 + r;
                    int w  = wbase_blk + s * 16 + l15;
                    out[((size_t)oc * NLAT_OUT + h) * NLON_OUT + w] = acc[hh][s][r];
                }
    }
}

// ---------------------------------------------------------------------------
extern "C" void kernel_launch(void* const* d_in, const int* in_sizes, int n_in,
                              void* d_out, int out_size, void* d_ws, size_t ws_size,
                              hipStream_t stream) {
    const float* x        = (const float*)d_in[0];
    const float* weight   = (const float*)d_in[1];
    const float* psi_vals = (const float*)d_in[2];
    const int*   psi_hi   = (const int*)d_in[3];
    const int*   psi_dw   = (const int*)d_in[4];
    float* out = (float*)d_out;

    // workspace: xr bf16 [721][1440][32] = 66,447,360 B, then
    // weff bf16 [721][20][32][32] = 29,532,160 B
    unsigned short* xr = (unsigned short*)d_ws;
    unsigned short* wf = (unsigned short*)((char*)d_ws + (size_t)NLAT_OUT * NLON_OUT * CH * 2);

    {
        pre_kernel<<<NBLK_WEFF + NBLK_RES, 256, 0, stream>>>(x, weight, psi_vals, xr, wf);
    }
    {
        disco_kernel<<<8 * PER_XCD, 256, 0, stream>>>(xr, wf, psi_hi, psi_dw, out);
    }
}